// Round 10
// baseline (165.713 us; speedup 1.0000x reference)
//
#include <hip/hip_runtime.h>

#define SEQ 512
#define BZ  64
#define DIN 1024
#define HID 256
#define DOUT 1024
#define NLANG 16

typedef __attribute__((ext_vector_type(8))) __bf16 bf16x8;
typedef __attribute__((ext_vector_type(4))) float f32x4;

__device__ __forceinline__ unsigned short f2bf(float f) {
    return __builtin_bit_cast(unsigned short, (__bf16)f);
}
__device__ __forceinline__ unsigned int f2bf_pack(float lo, float hi) {
    return (unsigned int)f2bf(lo) | ((unsigned int)f2bf(hi) << 16);
}
__device__ __forceinline__ void gload_lds16(const unsigned short* g, unsigned short* l) {
    __builtin_amdgcn_global_load_lds(
        (const __attribute__((address_space(1))) unsigned int*)g,
        (__attribute__((address_space(3))) unsigned int*)l, 16, 0, 0);
}

// W[lid][K][N] f32  ->  Wf[lid][N/16][K/32][64 lanes][8] bf16 (fragment-major).
// Fragment (n16,k32), lane l, elem j  =  W[lid][k32*32+(l>>4)*8+j][n16*16+(l&15)].
template<int K, int N>
__global__ __launch_bounds__(256)
void prep_frags(const float* __restrict__ src, unsigned short* __restrict__ dst) {
    constexpr int K32 = K / 32, N16 = N / 16;
    const int gid = blockIdx.x * 256 + threadIdx.x;
    const int l   = gid & 63;
    const int f   = gid >> 6;
    const int k32 = f & (K32 - 1);
    const int n16 = (f / K32) & (N16 - 1);
    const int lid = f / (K32 * N16);
    const float* s = src + ((long)lid * K + k32 * 32 + (l >> 4) * 8) * N + n16 * 16 + (l & 15);
    unsigned short o[8];
#pragma unroll
    for (int j = 0; j < 8; ++j) o[j] = f2bf(s[(long)j * N]);
    uint4 v;
    v.x = (unsigned int)o[0] | ((unsigned int)o[1] << 16);
    v.y = (unsigned int)o[2] | ((unsigned int)o[3] << 16);
    v.z = (unsigned int)o[4] | ((unsigned int)o[5] << 16);
    v.w = (unsigned int)o[6] | ((unsigned int)o[7] << 16);
    *(uint4*)(dst + (long)gid * 8) = v;
}

// ---------------- layer 1 ----------------
// h64x256 = relu(x @ W1 + b1). One block per (b, st), 8 waves.
// Inner loop identical to R7 phase 1. Result written as the pre-swizzled
// 32KB sH byte-image to h_ws[(b*8+st)*16384] with coalesced uint4 stores.
__global__ __launch_bounds__(512, 6)
void mlp_l1(const float* __restrict__ x,
            const unsigned short* __restrict__ W1f,
            const float* __restrict__ b1,
            const int* __restrict__ lang,
            unsigned short* __restrict__ h_ws) {
    __shared__ unsigned short sA[2][64 * 64];   // 2 x 8 KiB x-tile (bf16, swizzled)
    __shared__ unsigned short sH[64 * 256];     // 32 KiB h-tile (bf16, swizzled)
    char* cH = (char*)sH;

    const int b  = blockIdx.x;
    const int st = blockIdx.y;
    const int t  = threadIdx.x;
    const int l  = t & 63;
    const int w  = t >> 6;                      // 0..7
    const int lid = lang[b];
    const int s0  = st * 64;
    const long xstride = (long)BZ * DIN;
    const float* xb = x + (long)s0 * xstride + (long)b * DIN;

    const f32x4 z4 = {0.f, 0.f, 0.f, 0.f};

    f32x4 acc1[4][2];
#pragma unroll
    for (int mi = 0; mi < 4; ++mi)
#pragma unroll
        for (int ni = 0; ni < 2; ++ni) acc1[mi][ni] = z4;

    float4 xr[2];
#define LOADX(KT)                                                                  \
    {                                                                              \
        _Pragma("unroll")                                                          \
        for (int j = 0; j < 2; ++j) {                                              \
            int u = t + 512 * j, m = u >> 4, c4 = u & 15;                          \
            xr[j] = *(const float4*)(xb + (long)m * xstride + (KT) * 64 + c4 * 4); \
        }                                                                          \
    }
#define WRITEX(BUF)                                                               \
    {                                                                             \
        char* cA = (char*)sA[BUF];                                                \
        _Pragma("unroll")                                                         \
        for (int j = 0; j < 2; ++j) {                                             \
            int u = t + 512 * j, m = u >> 4, c4 = u & 15;                         \
            uint2 p;                                                              \
            p.x = f2bf_pack(xr[j].x, xr[j].y);                                    \
            p.y = f2bf_pack(xr[j].z, xr[j].w);                                    \
            *(uint2*)(cA + (((m * 128) + c4 * 8) ^ ((m & 7) << 4))) = p;          \
        }                                                                         \
    }

    const unsigned short* w1p = W1f + (((long)lid * 16 + w * 2) * 32) * 512 + (long)l * 8;
    // frag (ni, k32) at w1p + ni*16384 + k32*512   (shorts)

    float bvv[2];
#pragma unroll
    for (int ni = 0; ni < 2; ++ni)
        bvv[ni] = b1[lid * HID + w * 32 + ni * 16 + (l & 15)];

    LOADX(0);
    WRITEX(0);
    bf16x8 bvp[2][2];
#pragma unroll
    for (int ni = 0; ni < 2; ++ni)
        bvp[0][ni] = __builtin_bit_cast(bf16x8, *(const uint4*)(w1p + (long)ni * 16384));
    __syncthreads();

    for (int kt = 0; kt < 16; ++kt) {
        if (kt < 15) LOADX(kt + 1);
        char* cA = (char*)sA[kt & 1];
#pragma unroll
        for (int ks = 0; ks < 2; ++ks) {
            const int k32 = kt * 2 + ks;
            if (k32 < 31) {
#pragma unroll
                for (int ni = 0; ni < 2; ++ni)
                    bvp[(k32 + 1) & 1][ni] = __builtin_bit_cast(bf16x8,
                        *(const uint4*)(w1p + (long)ni * 16384 + (k32 + 1) * 512));
            }
            bf16x8 av[4];
#pragma unroll
            for (int mi = 0; mi < 4; ++mi) {
                int row = mi * 16 + (l & 15);
                int ch  = ks * 4 + (l >> 4);
                av[mi] = __builtin_bit_cast(bf16x8,
                    *(const uint4*)(cA + row * 128 + ((ch ^ (row & 7)) << 4)));
            }
#pragma unroll
            for (int mi = 0; mi < 4; ++mi)
#pragma unroll
                for (int ni = 0; ni < 2; ++ni)
                    acc1[mi][ni] = __builtin_amdgcn_mfma_f32_16x16x32_bf16(
                        av[mi], bvp[k32 & 1][ni], acc1[mi][ni], 0, 0, 0);
        }
        if (kt < 15) WRITEX((kt & 1) ^ 1);
        __syncthreads();
    }

    // epilogue: bias + relu + bf16 -> swizzled sH, then coalesced copy to h_ws
#pragma unroll
    for (int mi = 0; mi < 4; ++mi)
#pragma unroll
        for (int r = 0; r < 4; ++r) {
            int row = mi * 16 + (l >> 4) * 4 + r;
#pragma unroll
            for (int ni = 0; ni < 2; ++ni) {
                int col = w * 32 + ni * 16 + (l & 15);
                float v = acc1[mi][ni][r] + bvv[ni];
                v = v > 0.f ? v : 0.f;
                *(unsigned short*)(cH + row * 512 + (((col >> 3) ^ (row & 7)) << 4)
                                   + (col & 7) * 2) = f2bf(v);
            }
        }
    __syncthreads();

    uint4* hw = (uint4*)(h_ws + ((long)(b * 8 + st)) * 16384);
    const uint4* sq = (const uint4*)sH;
#pragma unroll
    for (int j = 0; j < 4; ++j)
        hw[t + 512 * j] = sq[t + 512 * j];
#undef LOADX
#undef WRITEX
}

// ---------------- layer 2 ----------------
// y64x1024 = h @ W2 + b2. One block per (b, st), 8 waves. Stages the
// pre-swizzled 32KB h image into LDS via linear global_load_lds, then runs
// R7's phase-2 loop unchanged (per wave 128 cols, depth-1 ping-pong).
__global__ __launch_bounds__(512, 4)
void mlp_l2(const unsigned short* __restrict__ h_ws,
            const unsigned short* __restrict__ W2f,
            const float* __restrict__ b2,
            const int* __restrict__ lang,
            float* __restrict__ y) {
    __shared__ unsigned short sH[64 * 256];     // 32 KiB h-tile (bf16, swizzled image)
    char* cH = (char*)sH;

    const int b  = blockIdx.x;
    const int st = blockIdx.y;
    const int t  = threadIdx.x;
    const int l  = t & 63;
    const int w  = t >> 6;                      // 0..7
    const int lid = lang[b];
    const int s0  = st * 64;

    const unsigned short* hw = h_ws + ((long)(b * 8 + st)) * 16384;
#pragma unroll
    for (int j = 0; j < 4; ++j) {
        int seg = w * 4 + j;                    // 1KB segments
        gload_lds16(hw + seg * 512 + l * 8, sH + seg * 512);
    }

    const unsigned short* w2p = W2f + (((long)lid * 64 + w * 8) * 8) * 512 + (long)l * 8;
    // frag (nc*4+ni, ks) at w2p + (nc*4+ni)*4096 + ks*512   (shorts)

    const f32x4 z4 = {0.f, 0.f, 0.f, 0.f};
    bf16x8 pv[2][4];
#pragma unroll
    for (int ni = 0; ni < 4; ++ni)
        pv[0][ni] = __builtin_bit_cast(bf16x8, *(const uint4*)(w2p + (long)ni * 4096));

    __syncthreads();   // drains vmcnt: h staging complete

    f32x4 acc[4][4];
    float b2v[4];
#pragma unroll
    for (int s = 0; s < 16; ++s) {
        const int nc = s >> 3, ks = s & 7, cur = s & 1;
        if (ks == 0) {
#pragma unroll
            for (int mi = 0; mi < 4; ++mi)
#pragma unroll
                for (int ni = 0; ni < 4; ++ni) acc[mi][ni] = z4;
#pragma unroll
            for (int ni = 0; ni < 4; ++ni)
                b2v[ni] = b2[lid * DOUT + w * 128 + nc * 64 + ni * 16 + (l & 15)];
        }
        if (s < 15) {
            const int ns = s + 1, nq = (ns >> 3) * 4, ks1 = ns & 7;
#pragma unroll
            for (int ni = 0; ni < 4; ++ni)
                pv[cur ^ 1][ni] = __builtin_bit_cast(bf16x8,
                    *(const uint4*)(w2p + (long)(nq + ni) * 4096 + ks1 * 512));
        }
        bf16x8 av2[4];
#pragma unroll
        for (int mi = 0; mi < 4; ++mi) {
            int row = mi * 16 + (l & 15);
            int ch  = ks * 4 + (l >> 4);
            av2[mi] = __builtin_bit_cast(bf16x8,
                *(const uint4*)(cH + row * 512 + ((ch ^ (row & 7)) << 4)));
        }
#pragma unroll
        for (int mi = 0; mi < 4; ++mi)
#pragma unroll
            for (int ni = 0; ni < 4; ++ni)
                acc[mi][ni] = __builtin_amdgcn_mfma_f32_16x16x32_bf16(
                    av2[mi], pv[cur][ni], acc[mi][ni], 0, 0, 0);
        if (ks == 7) {
#pragma unroll
            for (int mi = 0; mi < 4; ++mi)
#pragma unroll
                for (int r = 0; r < 4; ++r) {
                    int row = mi * 16 + (l >> 4) * 4 + r;
#pragma unroll
                    for (int ni = 0; ni < 4; ++ni) {
                        int col = w * 128 + nc * 64 + ni * 16 + (l & 15);
                        y[((long)(s0 + row) * BZ + b) * DOUT + col] =
                            acc[mi][ni][r] + b2v[ni];
                    }
                }
        }
    }
}

extern "C" void kernel_launch(void* const* d_in, const int* in_sizes, int n_in,
                              void* d_out, int out_size, void* d_ws, size_t ws_size,
                              hipStream_t stream) {
    const float* x    = (const float*)d_in[0];
    const int*   lang = (const int*)d_in[1];
    const float* W1   = (const float*)d_in[2];
    const float* b1   = (const float*)d_in[3];
    const float* W2   = (const float*)d_in[4];
    const float* b2   = (const float*)d_in[5];
    float* y = (float*)d_out;

    // ws: W1f bf16 (8 MiB) | W2f bf16 (8 MiB) | h image bf16 [64*8][16384] (16 MiB)
    unsigned short* W1f = (unsigned short*)d_ws;
    unsigned short* W2f = (unsigned short*)((char*)d_ws + (size_t)NLANG * HID * DIN * 2);
    unsigned short* hws = (unsigned short*)((char*)d_ws + (size_t)NLANG * HID * DIN * 2
                                                       + (size_t)NLANG * DOUT * HID * 2);

    prep_frags<DIN, HID><<<2048, 256, 0, stream>>>(W1, W1f);
    prep_frags<HID, DOUT><<<2048, 256, 0, stream>>>(W2, W2f);

    mlp_l1<<<dim3(BZ, SEQ / 64), 512, 0, stream>>>(x, W1f, b1, lang, hws);
    mlp_l2<<<dim3(BZ, SEQ / 64), 512, 0, stream>>>(hws, W2f, b2, lang, y);
}

// Round 11
// 118.191 us; speedup vs baseline: 1.4021x; 1.4021x over previous
//
#include <hip/hip_runtime.h>

#define SEQ 512
#define BZ  64
#define DIN 1024
#define HID 256
#define DOUT 1024
#define NLANG 16

typedef __attribute__((ext_vector_type(8))) __bf16 bf16x8;
typedef __attribute__((ext_vector_type(4))) float f32x4;

__device__ __forceinline__ unsigned short f2bf(float f) {
    return __builtin_bit_cast(unsigned short, (__bf16)f);
}
__device__ __forceinline__ unsigned int f2bf_pack(float lo, float hi) {
    return (unsigned int)f2bf(lo) | ((unsigned int)f2bf(hi) << 16);
}
__device__ __forceinline__ void gload_lds16(const unsigned short* g, unsigned short* l) {
    __builtin_amdgcn_global_load_lds(
        (const __attribute__((address_space(1))) unsigned int*)g,
        (__attribute__((address_space(3))) unsigned int*)l, 16, 0, 0);
}

// W[lid][K][N] f32  ->  Wf[lid][N/16][K/32][64 lanes][8] bf16 (fragment-major).
// Fragment (n16,k32), lane l, elem j  =  W[lid][k32*32+(l>>4)*8+j][n16*16+(l&15)].
template<int K, int N>
__global__ __launch_bounds__(256)
void prep_frags(const float* __restrict__ src, unsigned short* __restrict__ dst) {
    constexpr int K32 = K / 32, N16 = N / 16;
    const int gid = blockIdx.x * 256 + threadIdx.x;
    const int l   = gid & 63;
    const int f   = gid >> 6;
    const int k32 = f & (K32 - 1);
    const int n16 = (f / K32) & (N16 - 1);
    const int lid = f / (K32 * N16);
    const float* s = src + ((long)lid * K + k32 * 32 + (l >> 4) * 8) * N + n16 * 16 + (l & 15);
    unsigned short o[8];
#pragma unroll
    for (int j = 0; j < 8; ++j) o[j] = f2bf(s[(long)j * N]);
    uint4 v;
    v.x = (unsigned int)o[0] | ((unsigned int)o[1] << 16);
    v.y = (unsigned int)o[2] | ((unsigned int)o[3] << 16);
    v.z = (unsigned int)o[4] | ((unsigned int)o[5] << 16);
    v.w = (unsigned int)o[6] | ((unsigned int)o[7] << 16);
    *(uint4*)(dst + (long)gid * 8) = v;
}

// ---------------- layer 1 ----------------
// h64x256 = relu(x @ W1 + b1). One block per (b, st), 8 waves.
// BK=256: each kt reads 1 KB CONTIGUOUS per x row (one wave-load per row) to
// fix DRAM page granularity. 4 kt steps, single-buffered 32KB sX; LOADX(kt+1)
// issued before compute(kt) so HBM latency hides under the MFMA block.
__global__ __launch_bounds__(512, 2)
void mlp_l1(const float* __restrict__ x,
            const unsigned short* __restrict__ W1f,
            const float* __restrict__ b1,
            const int* __restrict__ lang,
            unsigned short* __restrict__ h_ws) {
    __shared__ unsigned short sX[64 * 256];     // 32 KiB x-tile (bf16, swizzled)
    __shared__ unsigned short sH[64 * 256];     // 32 KiB h-tile (bf16, swizzled)
    char* cX = (char*)sX;
    char* cH = (char*)sH;

    const int b  = blockIdx.x;
    const int st = blockIdx.y;
    const int t  = threadIdx.x;
    const int l  = t & 63;
    const int w  = t >> 6;                      // 0..7
    const int lid = lang[b];
    const long xstride = (long)BZ * DIN;
    const float* xb = x + (long)(st * 64) * xstride + (long)b * DIN;

    const f32x4 z4 = {0.f, 0.f, 0.f, 0.f};

    f32x4 acc1[4][2];
#pragma unroll
    for (int mi = 0; mi < 4; ++mi)
#pragma unroll
        for (int ni = 0; ni < 2; ++ni) acc1[mi][ni] = z4;

    float4 xr[8];
    // u = t + 512j: m = u>>6 (row), c4 = u&63 (float4 within the 1KB row chunk).
    // A wave (t 0..63 etc.) reads one row's 1KB contiguously.
#define LOADX(KT)                                                                   \
    {                                                                               \
        _Pragma("unroll")                                                           \
        for (int j = 0; j < 8; ++j) {                                               \
            int u = t + 512 * j, m = u >> 6, c4 = u & 63;                           \
            xr[j] = *(const float4*)(xb + (long)m * xstride + (KT) * 256 + c4 * 4); \
        }                                                                           \
    }
    // bf16 row = 512B; 16B chunk slot = (c4>>1) ^ (m&7); 8B half = c4&1.
#define WRITEX                                                                      \
    {                                                                               \
        _Pragma("unroll")                                                           \
        for (int j = 0; j < 8; ++j) {                                               \
            int u = t + 512 * j, m = u >> 6, c4 = u & 63;                           \
            uint2 p;                                                                \
            p.x = f2bf_pack(xr[j].x, xr[j].y);                                      \
            p.y = f2bf_pack(xr[j].z, xr[j].w);                                      \
            *(uint2*)(cX + m * 512 + (((c4 >> 1) ^ (m & 7)) << 4) + (c4 & 1) * 8) = p; \
        }                                                                           \
    }

    const unsigned short* w1p = W1f + (((long)lid * 16 + w * 2) * 32) * 512 + (long)l * 8;
    // frag (ni, k32) at w1p + ni*16384 + k32*512   (shorts)

    float bvv[2];
#pragma unroll
    for (int ni = 0; ni < 2; ++ni)
        bvv[ni] = b1[lid * HID + w * 32 + ni * 16 + (l & 15)];

    LOADX(0);
    bf16x8 bvp[2][2];
#pragma unroll
    for (int ni = 0; ni < 2; ++ni)
        bvp[0][ni] = __builtin_bit_cast(bf16x8, *(const uint4*)(w1p + (long)ni * 16384));
    WRITEX;
    __syncthreads();

#pragma unroll 1
    for (int kt = 0; kt < 4; ++kt) {
        if (kt < 3) LOADX(kt + 1);
#pragma unroll
        for (int ks = 0; ks < 8; ++ks) {
            const int k32 = kt * 8 + ks;
            if (k32 < 31) {
#pragma unroll
                for (int ni = 0; ni < 2; ++ni)
                    bvp[(k32 + 1) & 1][ni] = __builtin_bit_cast(bf16x8,
                        *(const uint4*)(w1p + (long)ni * 16384 + (k32 + 1) * 512));
            }
            bf16x8 av[4];
#pragma unroll
            for (int mi = 0; mi < 4; ++mi) {
                int row = mi * 16 + (l & 15);
                int ch  = ks * 4 + (l >> 4);
                av[mi] = __builtin_bit_cast(bf16x8,
                    *(const uint4*)(cX + row * 512 + ((ch ^ (row & 7)) << 4)));
            }
#pragma unroll
            for (int mi = 0; mi < 4; ++mi)
#pragma unroll
                for (int ni = 0; ni < 2; ++ni)
                    acc1[mi][ni] = __builtin_amdgcn_mfma_f32_16x16x32_bf16(
                        av[mi], bvp[k32 & 1][ni], acc1[mi][ni], 0, 0, 0);
        }
        if (kt < 3) {
            __syncthreads();   // all waves done reading sX
            WRITEX;
            __syncthreads();   // new tile visible
        }
    }

    // epilogue: bias + relu + bf16 -> swizzled sH, then coalesced copy to h_ws
    __syncthreads();
#pragma unroll
    for (int mi = 0; mi < 4; ++mi)
#pragma unroll
        for (int r = 0; r < 4; ++r) {
            int row = mi * 16 + (l >> 4) * 4 + r;
#pragma unroll
            for (int ni = 0; ni < 2; ++ni) {
                int col = w * 32 + ni * 16 + (l & 15);
                float v = acc1[mi][ni][r] + bvv[ni];
                v = v > 0.f ? v : 0.f;
                *(unsigned short*)(cH + row * 512 + (((col >> 3) ^ (row & 7)) << 4)
                                   + (col & 7) * 2) = f2bf(v);
            }
        }
    __syncthreads();

    uint4* hw = (uint4*)(h_ws + ((long)(b * 8 + st)) * 16384);
    const uint4* sq = (const uint4*)sH;
#pragma unroll
    for (int j = 0; j < 4; ++j)
        hw[t + 512 * j] = sq[t + 512 * j];
#undef LOADX
#undef WRITEX
}

// ---------------- layer 2 ----------------
// y64x1024 = h @ W2 + b2. One block per (b, st), 8 waves. Stages the
// pre-swizzled 32KB h image via linear global_load_lds, then R7's phase-2
// loop (per wave 128 cols, depth-1 ping-pong). launch_bounds (512,2): the
// (512,4) of R10 capped VGPR at 64 and spilled ~109MB to scratch.
__global__ __launch_bounds__(512, 2)
void mlp_l2(const unsigned short* __restrict__ h_ws,
            const unsigned short* __restrict__ W2f,
            const float* __restrict__ b2,
            const int* __restrict__ lang,
            float* __restrict__ y) {
    __shared__ unsigned short sH[64 * 256];     // 32 KiB h-tile (bf16, swizzled image)
    char* cH = (char*)sH;

    const int b  = blockIdx.x;
    const int st = blockIdx.y;
    const int t  = threadIdx.x;
    const int l  = t & 63;
    const int w  = t >> 6;                      // 0..7
    const int lid = lang[b];
    const int s0  = st * 64;

    const unsigned short* hw = h_ws + ((long)(b * 8 + st)) * 16384;
#pragma unroll
    for (int j = 0; j < 4; ++j) {
        int seg = w * 4 + j;                    // 1KB segments
        gload_lds16(hw + seg * 512 + l * 8, sH + seg * 512);
    }

    const unsigned short* w2p = W2f + (((long)lid * 64 + w * 8) * 8) * 512 + (long)l * 8;
    // frag (nc*4+ni, ks) at w2p + (nc*4+ni)*4096 + ks*512   (shorts)

    const f32x4 z4 = {0.f, 0.f, 0.f, 0.f};
    bf16x8 pv[2][4];
#pragma unroll
    for (int ni = 0; ni < 4; ++ni)
        pv[0][ni] = __builtin_bit_cast(bf16x8, *(const uint4*)(w2p + (long)ni * 4096));

    __syncthreads();   // drains vmcnt: h staging complete

    f32x4 acc[4][4];
    float b2v[4];
#pragma unroll
    for (int s = 0; s < 16; ++s) {
        const int nc = s >> 3, ks = s & 7, cur = s & 1;
        if (ks == 0) {
#pragma unroll
            for (int mi = 0; mi < 4; ++mi)
#pragma unroll
                for (int ni = 0; ni < 4; ++ni) acc[mi][ni] = z4;
#pragma unroll
            for (int ni = 0; ni < 4; ++ni)
                b2v[ni] = b2[lid * DOUT + w * 128 + nc * 64 + ni * 16 + (l & 15)];
        }
        if (s < 15) {
            const int ns = s + 1, nq = (ns >> 3) * 4, ks1 = ns & 7;
#pragma unroll
            for (int ni = 0; ni < 4; ++ni)
                pv[cur ^ 1][ni] = __builtin_bit_cast(bf16x8,
                    *(const uint4*)(w2p + (long)(nq + ni) * 4096 + ks1 * 512));
        }
        bf16x8 av2[4];
#pragma unroll
        for (int mi = 0; mi < 4; ++mi) {
            int row = mi * 16 + (l & 15);
            int ch  = ks * 4 + (l >> 4);
            av2[mi] = __builtin_bit_cast(bf16x8,
                *(const uint4*)(cH + row * 512 + ((ch ^ (row & 7)) << 4)));
        }
#pragma unroll
        for (int mi = 0; mi < 4; ++mi)
#pragma unroll
            for (int ni = 0; ni < 4; ++ni)
                acc[mi][ni] = __builtin_amdgcn_mfma_f32_16x16x32_bf16(
                    av2[mi], pv[cur][ni], acc[mi][ni], 0, 0, 0);
        if (ks == 7) {
#pragma unroll
            for (int mi = 0; mi < 4; ++mi)
#pragma unroll
                for (int r = 0; r < 4; ++r) {
                    int row = mi * 16 + (l >> 4) * 4 + r;
#pragma unroll
                    for (int ni = 0; ni < 4; ++ni) {
                        int col = w * 128 + nc * 64 + ni * 16 + (l & 15);
                        y[((long)(s0 + row) * BZ + b) * DOUT + col] =
                            acc[mi][ni][r] + b2v[ni];
                    }
                }
        }
    }
}

extern "C" void kernel_launch(void* const* d_in, const int* in_sizes, int n_in,
                              void* d_out, int out_size, void* d_ws, size_t ws_size,
                              hipStream_t stream) {
    const float* x    = (const float*)d_in[0];
    const int*   lang = (const int*)d_in[1];
    const float* W1   = (const float*)d_in[2];
    const float* b1   = (const float*)d_in[3];
    const float* W2   = (const float*)d_in[4];
    const float* b2   = (const float*)d_in[5];
    float* y = (float*)d_out;

    // ws: W1f bf16 (8 MiB) | W2f bf16 (8 MiB) | h image bf16 [64*8][16384] (16 MiB)
    unsigned short* W1f = (unsigned short*)d_ws;
    unsigned short* W2f = (unsigned short*)((char*)d_ws + (size_t)NLANG * HID * DIN * 2);
    unsigned short* hws = (unsigned short*)((char*)d_ws + (size_t)NLANG * HID * DIN * 2
                                                       + (size_t)NLANG * DOUT * HID * 2);

    prep_frags<DIN, HID><<<2048, 256, 0, stream>>>(W1, W1f);
    prep_frags<HID, DOUT><<<2048, 256, 0, stream>>>(W2, W2f);

    mlp_l1<<<dim3(BZ, SEQ / 64), 512, 0, stream>>>(x, W1f, b1, lang, hws);
    mlp_l2<<<dim3(BZ, SEQ / 64), 512, 0, stream>>>(hws, W2f, b2, lang, y);
}

// Round 12
// 104.679 us; speedup vs baseline: 1.5831x; 1.1291x over previous
//
#include <hip/hip_runtime.h>

#define SEQ 512
#define BZ  64
#define DIN 1024
#define HID 256
#define DOUT 1024
#define NLANG 16

typedef __attribute__((ext_vector_type(8))) __bf16 bf16x8;
typedef __attribute__((ext_vector_type(4))) float f32x4;

__device__ __forceinline__ unsigned short f2bf(float f) {
    return __builtin_bit_cast(unsigned short, (__bf16)f);
}
__device__ __forceinline__ unsigned int f2bf_pack(float lo, float hi) {
    return (unsigned int)f2bf(lo) | ((unsigned int)f2bf(hi) << 16);
}
__device__ __forceinline__ void gload_lds16(const unsigned short* g, unsigned short* l) {
    __builtin_amdgcn_global_load_lds(
        (const __attribute__((address_space(1))) unsigned int*)g,
        (__attribute__((address_space(3))) unsigned int*)l, 16, 0, 0);
}

// W[lid][K][N] f32  ->  Wf[lid][N/16][K/32][64 lanes][8] bf16 (fragment-major).
// Fragment (n16,k32), lane l, elem j  =  W[lid][k32*32+(l>>4)*8+j][n16*16+(l&15)].
template<int K, int N>
__global__ __launch_bounds__(256)
void prep_frags(const float* __restrict__ src, unsigned short* __restrict__ dst) {
    constexpr int K32 = K / 32, N16 = N / 16;
    const int gid = blockIdx.x * 256 + threadIdx.x;
    const int l   = gid & 63;
    const int f   = gid >> 6;
    const int k32 = f & (K32 - 1);
    const int n16 = (f / K32) & (N16 - 1);
    const int lid = f / (K32 * N16);
    const float* s = src + ((long)lid * K + k32 * 32 + (l >> 4) * 8) * N + n16 * 16 + (l & 15);
    unsigned short o[8];
#pragma unroll
    for (int j = 0; j < 8; ++j) o[j] = f2bf(s[(long)j * N]);
    uint4 v;
    v.x = (unsigned int)o[0] | ((unsigned int)o[1] << 16);
    v.y = (unsigned int)o[2] | ((unsigned int)o[3] << 16);
    v.z = (unsigned int)o[4] | ((unsigned int)o[5] << 16);
    v.w = (unsigned int)o[6] | ((unsigned int)o[7] << 16);
    *(uint4*)(dst + (long)gid * 8) = v;
}

// ---------------- layer 1 ----------------
// h64x256 = relu(x @ W1 + b1). One block per (b, st), 8 waves. BK=64
// double-buffered (R10 structure) + PER-BLOCK KT-PHASE STAGGER: block
// iterates kt in order (i+koff)&15 so concurrent blocks' 256B x-chunks
// cover all 16 offsets within each 4KB row (HBM channel bits 8-11 spread).
__global__ __launch_bounds__(512, 2)
void mlp_l1(const float* __restrict__ x,
            const unsigned short* __restrict__ W1f,
            const float* __restrict__ b1,
            const int* __restrict__ lang,
            unsigned short* __restrict__ h_ws) {
    __shared__ unsigned short sA[2][64 * 64];   // 2 x 8 KiB x-tile (bf16, swizzled)
    __shared__ unsigned short sH[64 * 256];     // 32 KiB h-tile (bf16, swizzled)
    char* cH = (char*)sH;

    const int b  = blockIdx.x;
    const int st = blockIdx.y;
    const int t  = threadIdx.x;
    const int l  = t & 63;
    const int w  = t >> 6;                      // 0..7
    const int lid  = lang[b];
    const int koff = (b + st) & 15;             // kt-phase stagger
    const long xstride = (long)BZ * DIN;
    const float* xb = x + (long)(st * 64) * xstride + (long)b * DIN;

    const f32x4 z4 = {0.f, 0.f, 0.f, 0.f};

    f32x4 acc1[4][2];
#pragma unroll
    for (int mi = 0; mi < 4; ++mi)
#pragma unroll
        for (int ni = 0; ni < 2; ++ni) acc1[mi][ni] = z4;

    float4 xr[2];
#define LOADX(KT)                                                                  \
    {                                                                              \
        _Pragma("unroll")                                                          \
        for (int j = 0; j < 2; ++j) {                                              \
            int u = t + 512 * j, m = u >> 4, c4 = u & 15;                          \
            xr[j] = *(const float4*)(xb + (long)m * xstride + (KT) * 64 + c4 * 4); \
        }                                                                          \
    }
#define WRITEX(BUF)                                                               \
    {                                                                             \
        char* cA = (char*)sA[BUF];                                                \
        _Pragma("unroll")                                                         \
        for (int j = 0; j < 2; ++j) {                                             \
            int u = t + 512 * j, m = u >> 4, c4 = u & 15;                         \
            uint2 p;                                                              \
            p.x = f2bf_pack(xr[j].x, xr[j].y);                                    \
            p.y = f2bf_pack(xr[j].z, xr[j].w);                                    \
            *(uint2*)(cA + (((m * 128) + c4 * 8) ^ ((m & 7) << 4))) = p;          \
        }                                                                         \
    }

    const unsigned short* w1p = W1f + (((long)lid * 16 + w * 2) * 32) * 512 + (long)l * 8;
    // frag (ni, k32) at w1p + ni*16384 + k32*512   (shorts)

    float bvv[2];
#pragma unroll
    for (int ni = 0; ni < 2; ++ni)
        bvv[ni] = b1[lid * HID + w * 32 + ni * 16 + (l & 15)];

    LOADX(koff);                                // tile for i=0 (kt = koff)
    WRITEX(0);
    bf16x8 bvp[2][2];
#pragma unroll
    for (int ni = 0; ni < 2; ++ni)
        bvp[0][ni] = __builtin_bit_cast(bf16x8,
            *(const uint4*)(w1p + (long)ni * 16384 + ((koff * 2) & 31) * 512));
    __syncthreads();

    for (int i = 0; i < 16; ++i) {
        if (i < 15) LOADX((i + 1 + koff) & 15);
        char* cA = (char*)sA[i & 1];
#pragma unroll
        for (int ks = 0; ks < 2; ++ks) {
            const int p = i * 2 + ks;           // sequence position 0..31
            if (p < 31) {
                const int k32n = (p + 1 + koff * 2) & 31;
#pragma unroll
                for (int ni = 0; ni < 2; ++ni)
                    bvp[(p + 1) & 1][ni] = __builtin_bit_cast(bf16x8,
                        *(const uint4*)(w1p + (long)ni * 16384 + k32n * 512));
            }
            bf16x8 av[4];
#pragma unroll
            for (int mi = 0; mi < 4; ++mi) {
                int row = mi * 16 + (l & 15);
                int ch  = ks * 4 + (l >> 4);
                av[mi] = __builtin_bit_cast(bf16x8,
                    *(const uint4*)(cA + row * 128 + ((ch ^ (row & 7)) << 4)));
            }
#pragma unroll
            for (int mi = 0; mi < 4; ++mi)
#pragma unroll
                for (int ni = 0; ni < 2; ++ni)
                    acc1[mi][ni] = __builtin_amdgcn_mfma_f32_16x16x32_bf16(
                        av[mi], bvp[p & 1][ni], acc1[mi][ni], 0, 0, 0);
        }
        if (i < 15) WRITEX((i & 1) ^ 1);
        __syncthreads();
    }

    // epilogue: bias + relu + bf16 -> swizzled sH, then coalesced copy to h_ws
#pragma unroll
    for (int mi = 0; mi < 4; ++mi)
#pragma unroll
        for (int r = 0; r < 4; ++r) {
            int row = mi * 16 + (l >> 4) * 4 + r;
#pragma unroll
            for (int ni = 0; ni < 2; ++ni) {
                int col = w * 32 + ni * 16 + (l & 15);
                float v = acc1[mi][ni][r] + bvv[ni];
                v = v > 0.f ? v : 0.f;
                *(unsigned short*)(cH + row * 512 + (((col >> 3) ^ (row & 7)) << 4)
                                   + (col & 7) * 2) = f2bf(v);
            }
        }
    __syncthreads();

    uint4* hw = (uint4*)(h_ws + ((long)(b * 8 + st)) * 16384);
    const uint4* sq = (const uint4*)sH;
#pragma unroll
    for (int j = 0; j < 4; ++j)
        hw[t + 512 * j] = sq[t + 512 * j];
#undef LOADX
#undef WRITEX
}

// ---------------- layer 2 ----------------
// y64x1024 = h @ W2 + b2. One block per (b, st), 8 waves. Stages the
// pre-swizzled 32KB h image via linear global_load_lds, then the R7 phase-2
// loop (per wave 128 cols, depth-1 ping-pong). (512,2): R10's (512,4)
// capped VGPR at 64 and spilled ~109MB/dispatch to scratch.
__global__ __launch_bounds__(512, 2)
void mlp_l2(const unsigned short* __restrict__ h_ws,
            const unsigned short* __restrict__ W2f,
            const float* __restrict__ b2,
            const int* __restrict__ lang,
            float* __restrict__ y) {
    __shared__ unsigned short sH[64 * 256];     // 32 KiB h-tile (bf16, swizzled image)
    char* cH = (char*)sH;

    const int b  = blockIdx.x;
    const int st = blockIdx.y;
    const int t  = threadIdx.x;
    const int l  = t & 63;
    const int w  = t >> 6;                      // 0..7
    const int lid = lang[b];
    const int s0  = st * 64;

    const unsigned short* hw = h_ws + ((long)(b * 8 + st)) * 16384;
#pragma unroll
    for (int j = 0; j < 4; ++j) {
        int seg = w * 4 + j;                    // 1KB segments
        gload_lds16(hw + seg * 512 + l * 8, sH + seg * 512);
    }

    const unsigned short* w2p = W2f + (((long)lid * 64 + w * 8) * 8) * 512 + (long)l * 8;
    // frag (nc*4+ni, ks) at w2p + (nc*4+ni)*4096 + ks*512   (shorts)

    const f32x4 z4 = {0.f, 0.f, 0.f, 0.f};
    bf16x8 pv[2][4];
#pragma unroll
    for (int ni = 0; ni < 4; ++ni)
        pv[0][ni] = __builtin_bit_cast(bf16x8, *(const uint4*)(w2p + (long)ni * 4096));

    __syncthreads();   // drains vmcnt: h staging complete

    f32x4 acc[4][4];
    float b2v[4];
#pragma unroll
    for (int s = 0; s < 16; ++s) {
        const int nc = s >> 3, ks = s & 7, cur = s & 1;
        if (ks == 0) {
#pragma unroll
            for (int mi = 0; mi < 4; ++mi)
#pragma unroll
                for (int ni = 0; ni < 4; ++ni) acc[mi][ni] = z4;
#pragma unroll
            for (int ni = 0; ni < 4; ++ni)
                b2v[ni] = b2[lid * DOUT + w * 128 + nc * 64 + ni * 16 + (l & 15)];
        }
        if (s < 15) {
            const int ns = s + 1, nq = (ns >> 3) * 4, ks1 = ns & 7;
#pragma unroll
            for (int ni = 0; ni < 4; ++ni)
                pv[cur ^ 1][ni] = __builtin_bit_cast(bf16x8,
                    *(const uint4*)(w2p + (long)(nq + ni) * 4096 + ks1 * 512));
        }
        bf16x8 av2[4];
#pragma unroll
        for (int mi = 0; mi < 4; ++mi) {
            int row = mi * 16 + (l & 15);
            int ch  = ks * 4 + (l >> 4);
            av2[mi] = __builtin_bit_cast(bf16x8,
                *(const uint4*)(cH + row * 512 + ((ch ^ (row & 7)) << 4)));
        }
#pragma unroll
        for (int mi = 0; mi < 4; ++mi)
#pragma unroll
            for (int ni = 0; ni < 4; ++ni)
                acc[mi][ni] = __builtin_amdgcn_mfma_f32_16x16x32_bf16(
                    av2[mi], pv[cur][ni], acc[mi][ni], 0, 0, 0);
        if (ks == 7) {
#pragma unroll
            for (int mi = 0; mi < 4; ++mi)
#pragma unroll
                for (int r = 0; r < 4; ++r) {
                    int row = mi * 16 + (l >> 4) * 4 + r;
#pragma unroll
                    for (int ni = 0; ni < 4; ++ni) {
                        int col = w * 128 + nc * 64 + ni * 16 + (l & 15);
                        y[((long)(s0 + row) * BZ + b) * DOUT + col] =
                            acc[mi][ni][r] + b2v[ni];
                    }
                }
        }
    }
}

extern "C" void kernel_launch(void* const* d_in, const int* in_sizes, int n_in,
                              void* d_out, int out_size, void* d_ws, size_t ws_size,
                              hipStream_t stream) {
    const float* x    = (const float*)d_in[0];
    const int*   lang = (const int*)d_in[1];
    const float* W1   = (const float*)d_in[2];
    const float* b1   = (const float*)d_in[3];
    const float* W2   = (const float*)d_in[4];
    const float* b2   = (const float*)d_in[5];
    float* y = (float*)d_out;

    // ws: W1f bf16 (8 MiB) | W2f bf16 (8 MiB) | h image bf16 [64*8][16384] (16 MiB)
    unsigned short* W1f = (unsigned short*)d_ws;
    unsigned short* W2f = (unsigned short*)((char*)d_ws + (size_t)NLANG * HID * DIN * 2);
    unsigned short* hws = (unsigned short*)((char*)d_ws + (size_t)NLANG * HID * DIN * 2
                                                       + (size_t)NLANG * DOUT * HID * 2);

    prep_frags<DIN, HID><<<2048, 256, 0, stream>>>(W1, W1f);
    prep_frags<HID, DOUT><<<2048, 256, 0, stream>>>(W2, W2f);

    mlp_l1<<<dim3(BZ, SEQ / 64), 512, 0, stream>>>(x, W1f, b1, lang, hws);
    mlp_l2<<<dim3(BZ, SEQ / 64), 512, 0, stream>>>(hws, W2f, b2, lang, y);
}

// Round 13
// 102.896 us; speedup vs baseline: 1.6105x; 1.0173x over previous
//
#include <hip/hip_runtime.h>

#define SEQ 512
#define BZ  64
#define DIN 1024
#define HID 256
#define DOUT 1024
#define NLANG 16

typedef __attribute__((ext_vector_type(8))) __bf16 bf16x8;
typedef __attribute__((ext_vector_type(4))) float f32x4;

__device__ __forceinline__ unsigned short f2bf(float f) {
    return __builtin_bit_cast(unsigned short, (__bf16)f);
}
__device__ __forceinline__ unsigned int f2bf_pack(float lo, float hi) {
    return (unsigned int)f2bf(lo) | ((unsigned int)f2bf(hi) << 16);
}

// W[lid][K][N] f32  ->  Wf[lid][N/16][K/32][64 lanes][8] bf16 (fragment-major).
// Fragment (n16,k32), lane l, elem j  =  W[lid][k32*32+(l>>4)*8+j][n16*16+(l&15)].
template<int K, int N>
__global__ __launch_bounds__(256)
void prep_frags(const float* __restrict__ src, unsigned short* __restrict__ dst) {
    constexpr int K32 = K / 32, N16 = N / 16;
    const int gid = blockIdx.x * 256 + threadIdx.x;
    const int l   = gid & 63;
    const int f   = gid >> 6;
    const int k32 = f & (K32 - 1);
    const int n16 = (f / K32) & (N16 - 1);
    const int lid = f / (K32 * N16);
    const float* s = src + ((long)lid * K + k32 * 32 + (l >> 4) * 8) * N + n16 * 16 + (l & 15);
    unsigned short o[8];
#pragma unroll
    for (int j = 0; j < 8; ++j) o[j] = f2bf(s[(long)j * N]);
    uint4 v;
    v.x = (unsigned int)o[0] | ((unsigned int)o[1] << 16);
    v.y = (unsigned int)o[2] | ((unsigned int)o[3] << 16);
    v.z = (unsigned int)o[4] | ((unsigned int)o[5] << 16);
    v.w = (unsigned int)o[6] | ((unsigned int)o[7] << 16);
    *(uint4*)(dst + (long)gid * 8) = v;
}

// Fused per-language MLP. One block per (b, st): 64 seq rows, 8 waves (512 thr).
// = the 96us R7 kernel with ONE mechanism changed: W-fragment prefetch depth.
// Phase-1 bvp ring 2->4 (distance 3), phase-2 pv ring 2->3 (distance 2).
// Rationale: l1/l2 split showed ~4500-4900 cy per W-frag step in BOTH layers
// (~10x the compute content) -> depth-1 ping-pong exposes L2/L3 latency.
__global__ __launch_bounds__(512, 2)
void fused_mlp(const float* __restrict__ x,
               const unsigned short* __restrict__ W1f,
               const float* __restrict__ b1,
               const unsigned short* __restrict__ W2f,
               const float* __restrict__ b2,
               const int* __restrict__ lang,
               float* __restrict__ y) {
    __shared__ unsigned short sA[2][64 * 64];   // 2 x 8 KiB x-tile (bf16, swizzled)
    __shared__ unsigned short sH[64 * 256];     // 32 KiB h-tile (bf16, swizzled)
    char* cH = (char*)sH;

    const int b  = blockIdx.x;
    const int st = blockIdx.y;
    const int t  = threadIdx.x;
    const int l  = t & 63;
    const int w  = t >> 6;                      // 0..7
    const int lid = lang[b];
    const int s0  = st * 64;
    const long xstride = (long)BZ * DIN;
    const float* xb = x + (long)s0 * xstride + (long)b * DIN;

    const f32x4 z4 = {0.f, 0.f, 0.f, 0.f};

    // ---------------- phase 1 ----------------
    f32x4 acc1[4][2];
#pragma unroll
    for (int mi = 0; mi < 4; ++mi)
#pragma unroll
        for (int ni = 0; ni < 2; ++ni) acc1[mi][ni] = z4;

    float4 xr[2];
#define LOADX(KT)                                                                  \
    {                                                                              \
        _Pragma("unroll")                                                          \
        for (int j = 0; j < 2; ++j) {                                              \
            int u = t + 512 * j, m = u >> 4, c4 = u & 15;                          \
            xr[j] = *(const float4*)(xb + (long)m * xstride + (KT) * 64 + c4 * 4); \
        }                                                                          \
    }
#define WRITEX(BUF)                                                               \
    {                                                                             \
        char* cA = (char*)sA[BUF];                                                \
        _Pragma("unroll")                                                         \
        for (int j = 0; j < 2; ++j) {                                             \
            int u = t + 512 * j, m = u >> 4, c4 = u & 15;                         \
            uint2 p;                                                              \
            p.x = f2bf_pack(xr[j].x, xr[j].y);                                    \
            p.y = f2bf_pack(xr[j].z, xr[j].w);                                    \
            *(uint2*)(cA + (((m * 128) + c4 * 8) ^ ((m & 7) << 4))) = p;          \
        }                                                                         \
    }

    const unsigned short* w1p = W1f + (((long)lid * 16 + w * 2) * 32) * 512 + (long)l * 8;
    // frag (ni, k32) at w1p + ni*16384 + k32*512   (shorts)

    float bvv[2];
#pragma unroll
    for (int ni = 0; ni < 2; ++ni)
        bvv[ni] = b1[lid * HID + w * 32 + ni * 16 + (l & 15)];

    LOADX(0);
    WRITEX(0);
    // ring-4 W1-frag prefetch, distance 3: prologue loads k32 = 0,1,2
    bf16x8 bvp[4][2];
#pragma unroll
    for (int s = 0; s < 3; ++s)
#pragma unroll
        for (int ni = 0; ni < 2; ++ni)
            bvp[s][ni] = __builtin_bit_cast(bf16x8,
                *(const uint4*)(w1p + (long)ni * 16384 + s * 512));
    __syncthreads();

#pragma unroll 4
    for (int kt = 0; kt < 16; ++kt) {
        if (kt < 15) LOADX(kt + 1);
        char* cA = (char*)sA[kt & 1];
#pragma unroll
        for (int ks = 0; ks < 2; ++ks) {
            const int p = kt * 2 + ks;          // 0..31 (static mod 4 via unroll)
            if (p < 29) {
#pragma unroll
                for (int ni = 0; ni < 2; ++ni)
                    bvp[(p + 3) & 3][ni] = __builtin_bit_cast(bf16x8,
                        *(const uint4*)(w1p + (long)ni * 16384 + (p + 3) * 512));
            }
            bf16x8 av[4];
#pragma unroll
            for (int mi = 0; mi < 4; ++mi) {
                int row = mi * 16 + (l & 15);
                int ch  = ks * 4 + (l >> 4);
                av[mi] = __builtin_bit_cast(bf16x8,
                    *(const uint4*)(cA + row * 128 + ((ch ^ (row & 7)) << 4)));
            }
#pragma unroll
            for (int mi = 0; mi < 4; ++mi)
#pragma unroll
                for (int ni = 0; ni < 2; ++ni)
                    acc1[mi][ni] = __builtin_amdgcn_mfma_f32_16x16x32_bf16(
                        av[mi], bvp[p & 3][ni], acc1[mi][ni], 0, 0, 0);
        }
        if (kt < 15) WRITEX((kt & 1) ^ 1);
        __syncthreads();
    }

    // epilogue 1: bias + relu + bf16 -> swizzled sH
#pragma unroll
    for (int mi = 0; mi < 4; ++mi)
#pragma unroll
        for (int r = 0; r < 4; ++r) {
            int row = mi * 16 + (l >> 4) * 4 + r;
#pragma unroll
            for (int ni = 0; ni < 2; ++ni) {
                int col = w * 32 + ni * 16 + (l & 15);
                float v = acc1[mi][ni][r] + bvv[ni];
                v = v > 0.f ? v : 0.f;
                *(unsigned short*)(cH + row * 512 + (((col >> 3) ^ (row & 7)) << 4)
                                   + (col & 7) * 2) = f2bf(v);
            }
        }
    __syncthreads();

    // ---------------- phase 2 ----------------
    const unsigned short* w2p = W2f + (((long)lid * 64 + w * 8) * 8) * 512 + (long)l * 8;
    // frag (nc*4+ni, ks) at w2p + (nc*4+ni)*4096 + ks*512   (shorts)

    // ring-3 W2-frag prefetch, distance 2: prologue loads steps 0,1
    bf16x8 pv[3][4];
#pragma unroll
    for (int s = 0; s < 2; ++s) {
        const int nq = (s >> 3) * 4, ks1 = s & 7;
#pragma unroll
        for (int ni = 0; ni < 4; ++ni)
            pv[s][ni] = __builtin_bit_cast(bf16x8,
                *(const uint4*)(w2p + (long)(nq + ni) * 4096 + ks1 * 512));
    }

    f32x4 acc[4][4];
    float b2v[4];
#pragma unroll
    for (int s = 0; s < 16; ++s) {
        const int nc = s >> 3, ks = s & 7;
        if (ks == 0) {
#pragma unroll
            for (int mi = 0; mi < 4; ++mi)
#pragma unroll
                for (int ni = 0; ni < 4; ++ni) acc[mi][ni] = z4;
#pragma unroll
            for (int ni = 0; ni < 4; ++ni)
                b2v[ni] = b2[lid * DOUT + w * 128 + nc * 64 + ni * 16 + (l & 15)];
        }
        if (s < 14) {
            const int ns = s + 2, nq = (ns >> 3) * 4, ks1 = ns & 7;
#pragma unroll
            for (int ni = 0; ni < 4; ++ni)
                pv[ns % 3][ni] = __builtin_bit_cast(bf16x8,
                    *(const uint4*)(w2p + (long)(nq + ni) * 4096 + ks1 * 512));
        }
        bf16x8 av2[4];
#pragma unroll
        for (int mi = 0; mi < 4; ++mi) {
            int row = mi * 16 + (l & 15);
            int ch  = ks * 4 + (l >> 4);
            av2[mi] = __builtin_bit_cast(bf16x8,
                *(const uint4*)(cH + row * 512 + ((ch ^ (row & 7)) << 4)));
        }
#pragma unroll
        for (int mi = 0; mi < 4; ++mi)
#pragma unroll
            for (int ni = 0; ni < 4; ++ni)
                acc[mi][ni] = __builtin_amdgcn_mfma_f32_16x16x32_bf16(
                    av2[mi], pv[s % 3][ni], acc[mi][ni], 0, 0, 0);
        if (ks == 7) {
#pragma unroll
            for (int mi = 0; mi < 4; ++mi)
#pragma unroll
                for (int r = 0; r < 4; ++r) {
                    int row = mi * 16 + (l >> 4) * 4 + r;
#pragma unroll
                    for (int ni = 0; ni < 4; ++ni) {
                        int col = w * 128 + nc * 64 + ni * 16 + (l & 15);
                        y[((long)(s0 + row) * BZ + b) * DOUT + col] =
                            acc[mi][ni][r] + b2v[ni];
                    }
                }
        }
    }
#undef LOADX
#undef WRITEX
}

extern "C" void kernel_launch(void* const* d_in, const int* in_sizes, int n_in,
                              void* d_out, int out_size, void* d_ws, size_t ws_size,
                              hipStream_t stream) {
    const float* x    = (const float*)d_in[0];
    const int*   lang = (const int*)d_in[1];
    const float* W1   = (const float*)d_in[2];
    const float* b1   = (const float*)d_in[3];
    const float* W2   = (const float*)d_in[4];
    const float* b2   = (const float*)d_in[5];
    float* y = (float*)d_out;

    // ws: W1f bf16 [16][16][32][64][8] (8 MiB) | W2f bf16 [16][64][8][64][8] (8 MiB)
    unsigned short* W1f = (unsigned short*)d_ws;
    unsigned short* W2f = (unsigned short*)((char*)d_ws + (size_t)NLANG * HID * DIN * 2);

    prep_frags<DIN, HID><<<2048, 256, 0, stream>>>(W1, W1f);
    prep_frags<HID, DOUT><<<2048, 256, 0, stream>>>(W2, W2f);

    fused_mlp<<<dim3(BZ, SEQ / 64), 512, 0, stream>>>(x, W1f, b1, W2f, b2, lang, y);
}